// Round 1
// baseline (109.554 us; speedup 1.0000x reference)
//
#include <hip/hip_runtime.h>

// HDC encode + classify, fully fused.
// Math: idx = clip(rint(x/20*20),0,20); samples[b,t,d] = ts[t,d] * sum_l cnt[b,t,l]*sig[l,d]
//       hv[b,d] = sum_{j=0}^{124} prod_{i=0}^{3} samples[b,j+i,(d-3+i) mod D]
//       out[b,k] = sum_d sign(hv[b,d]) * cw[k,d]
// All intermediate values are exact small integers (±1 hvs, counts<=32,
// |4-gram product| <= 32^4, |sum of 125| << 2^24) -> sign matches reference exactly.

#define D_ 10000
#define NL_ 21
#define B_ 4
#define T_ 128
#define C_ 32
#define NC_ 10
#define TD_ 80            // d-columns per tile
#define NT_ 125           // tiles per batch (125*80 = 10000)
#define COLS_ (TD_ + 3)   // 83 incl. left halo of 3
#define CPAD_ 84

__global__ __launch_bounds__(256)
void hdc_fused(const float* __restrict__ x,
               const float* __restrict__ sig,
               const float* __restrict__ ts,
               const float* __restrict__ cw,
               float* __restrict__ out) {
    __shared__ float cnt[T_][NL_];        // 10752 B
    __shared__ float sig_s[NL_][CPAD_];   //  7056 B
    __shared__ float smp[T_][CPAD_];      // 43008 B
    __shared__ float part_j[2 * TD_];     //   640 B
    __shared__ float part_k[4][NC_];      //   160 B

    const int tid   = threadIdx.x;
    const int b     = blockIdx.x / NT_;
    const int tile  = blockIdx.x % NT_;
    const int start = tile * TD_;

    // ---- phase 1: per-(b,t) level histogram ----
    for (int w = tid; w < T_ * NL_; w += 256) ((float*)cnt)[w] = 0.0f;
    __syncthreads();
    for (int w = tid; w < T_ * C_; w += 256) {
        float xv = x[b * T_ * C_ + w];
        float t2 = (xv / 20.0f) * 20.0f;      // replicate ref op order
        float r  = rintf(t2);                 // round-half-even, matches jnp.round
        r = fminf(fmaxf(r, 0.0f), 20.0f);
        int lvl = (int)r;
        int t   = w >> 5;                     // w / C
        atomicAdd(&cnt[t][lvl], 1.0f);
    }
    // ---- phase 2: stage signals_w slab (with halo, wrap left edge) ----
    for (int w = tid; w < NL_ * COLS_; w += 256) {
        int l = w / COLS_, col = w - l * COLS_;
        int dd = start - 3 + col; if (dd < 0) dd += D_;
        sig_s[l][col] = sig[l * D_ + dd];
    }
    __syncthreads();
    // ---- phase 3: samples = ts * (cnt . sig) ----
    for (int w = tid; w < T_ * COLS_; w += 256) {
        int t = w / COLS_, col = w - t * COLS_;
        int dd = start - 3 + col; if (dd < 0) dd += D_;
        float acc = 0.0f;
        #pragma unroll
        for (int l = 0; l < NL_; ++l) acc += cnt[t][l] * sig_s[l][col];
        smp[t][col] = ts[t * D_ + dd] * acc;
    }
    __syncthreads();
    // ---- phase 4: 4-gram bind + bundle over j (split j-range 2-way per d) ----
    if (tid < 2 * TD_) {
        int od = tid >> 1, half = tid & 1;
        int j0 = half ? 63 : 0;
        int j1 = half ? 125 : 63;
        float acc = 0.0f;
        for (int j = j0; j < j1; ++j) {
            acc += smp[j][od] * smp[j + 1][od + 1] * smp[j + 2][od + 2] * smp[j + 3][od + 3];
        }
        part_j[tid] = acc;
    }
    __syncthreads();
    float enc = 0.0f;
    if (tid < TD_) {
        float tot = part_j[2 * tid] + part_j[2 * tid + 1];
        enc = (tot > 0.0f) ? 1.0f : -1.0f;    // hard_quantize (==0 -> -1)
    }
    // ---- phase 5: classify partials, wave-shuffle reduce, one atomic per class ----
    const int wave = tid >> 6;
    const int lane = tid & 63;
    #pragma unroll
    for (int k = 0; k < NC_; ++k) {
        float contrib = (tid < TD_) ? enc * cw[k * D_ + start + tid] : 0.0f;
        #pragma unroll
        for (int m = 32; m >= 1; m >>= 1) contrib += __shfl_xor(contrib, m, 64);
        if (lane == 0) part_k[wave][k] = contrib;
    }
    __syncthreads();
    if (tid < NC_) {
        float s = part_k[0][tid] + part_k[1][tid] + part_k[2][tid] + part_k[3][tid];
        atomicAdd(&out[b * NC_ + tid], s);
    }
}

extern "C" void kernel_launch(void* const* d_in, const int* in_sizes, int n_in,
                              void* d_out, int out_size, void* d_ws, size_t ws_size,
                              hipStream_t stream) {
    const float* x   = (const float*)d_in[0];
    const float* sig = (const float*)d_in[1];
    // d_in[2] = channels_w: dead bind in the reference, intentionally unused
    const float* ts  = (const float*)d_in[3];
    const float* cw  = (const float*)d_in[4];
    float* out = (float*)d_out;

    hipMemsetAsync(out, 0, (size_t)out_size * sizeof(float), stream);
    hdc_fused<<<B_ * NT_, 256, 0, stream>>>(x, sig, ts, cw, out);
}